// Round 4
// baseline (488.742 us; speedup 1.0000x reference)
//
#include <hip/hip_runtime.h>
#include <hip/hip_bf16.h>
#include <math.h>

// Problem constants
#define B_DIM 4
#define T_DIM 1024
#define D_DIM 1024
#define M_DIM 16
#define H_DIM 64
#define NT    4096            // B*T
#define NA    17408           // H*M*(M+1)
#define EPSV  1e-5f

typedef __bf16 bf16_t;
typedef __bf16 bf16x4 __attribute__((ext_vector_type(4)));
typedef __bf16 bf16x8 __attribute__((ext_vector_type(8)));
typedef float  f32x4  __attribute__((ext_vector_type(4)));

// ---------------------------------------------------------------------------
// fp32 -> bf16 conversion (grid-stride, float4 vectorized)
// ---------------------------------------------------------------------------
__global__ __launch_bounds__(256) void cvt_kernel(const float* __restrict__ in,
                                                  bf16_t* __restrict__ out, int n4) {
  int idx = blockIdx.x * blockDim.x + threadIdx.x;
  int stride = gridDim.x * blockDim.x;
  for (; idx < n4; idx += stride) {
    float4 v = reinterpret_cast<const float4*>(in)[idx];
    bf16x4 o;
    o[0] = (bf16_t)v.x; o[1] = (bf16_t)v.y; o[2] = (bf16_t)v.z; o[3] = (bf16_t)v.w;
    reinterpret_cast<bf16x4*>(out)[idx] = o;
  }
}

// ---------------------------------------------------------------------------
// RMSNorm: one block (256 thr) per row of 1024; output bf16
// ---------------------------------------------------------------------------
__global__ __launch_bounds__(256) void rmsnorm_kernel(const float* __restrict__ x,
                                                      const float* __restrict__ w,
                                                      bf16_t* __restrict__ h) {
  int row = blockIdx.x;
  int tid = threadIdx.x;
  const float4* xr = reinterpret_cast<const float4*>(x + (size_t)row * D_DIM);
  float4 xv = xr[tid];
  float ss = xv.x * xv.x + xv.y * xv.y + xv.z * xv.z + xv.w * xv.w;
#pragma unroll
  for (int m = 1; m < 64; m <<= 1) ss += __shfl_xor(ss, m, 64);
  __shared__ float red[4];
  int lane = tid & 63, wid = tid >> 6;
  if (lane == 0) red[wid] = ss;
  __syncthreads();
  float tot = red[0] + red[1] + red[2] + red[3];
  float scale = rsqrtf(tot * (1.0f / D_DIM) + EPSV);
  float4 wv = reinterpret_cast<const float4*>(w)[tid];
  bf16x4 o;
  o[0] = (bf16_t)(xv.x * scale * wv.x);
  o[1] = (bf16_t)(xv.y * scale * wv.y);
  o[2] = (bf16_t)(xv.z * scale * wv.z);
  o[3] = (bf16_t)(xv.w * scale * wv.w);
  reinterpret_cast<bf16x4*>(h)[(size_t)row * 256 + tid] = o;
}

// ---------------------------------------------------------------------------
// NT GEMM: C[M,N] = A[M,K] * Bw[N,K]^T   (bf16 in, fp32 accum)
// 128x128 tile, BK=32, 4 waves (2x2). R1 structure (known 211 us on logits).
// OUT_MODE: 0 = f32 out, 1 = bf16 out, 2 = f32 out + residual add
// ---------------------------------------------------------------------------
template <int OUT_MODE>
__global__ __launch_bounds__(256) void gemm_nt_kernel(const bf16_t* __restrict__ A,
                                                      const bf16_t* __restrict__ Bw,
                                                      void* __restrict__ Cout,
                                                      const float* __restrict__ resid,
                                                      int Mdim, int Ndim, int K) {
  constexpr int BM = 128, BN = 128, BK = 32;
  __shared__ bf16_t As[BM * BK];
  __shared__ bf16_t Bs[BN * BK];

  int tid = threadIdx.x;
  int lane = tid & 63;
  int wid = tid >> 6;           // 0..3
  int wm = wid >> 1, wn = wid & 1;
  int bm = blockIdx.x * BM;
  int bn = blockIdx.y * BN;
  int l15 = lane & 15;
  int l4 = lane >> 4;

  f32x4 acc[4][4];
#pragma unroll
  for (int i = 0; i < 4; i++)
#pragma unroll
    for (int j = 0; j < 4; j++) acc[i][j] = (f32x4){0.f, 0.f, 0.f, 0.f};

  const bf16_t* Ag = A + (size_t)bm * K;
  const bf16_t* Bg = Bw + (size_t)bn * K;
  int srow_lane = lane >> 2;          // 0..15
  int scol = (lane & 3) * 8;          // element col offset

  for (int k0 = 0; k0 < K; k0 += BK) {
#pragma unroll
    for (int i = 0; i < 2; i++) {
      int rbase = wid * 32 + i * 16;
      int r = rbase + srow_lane;
      __builtin_amdgcn_global_load_lds(
          (const __attribute__((address_space(1))) void*)(Ag + (size_t)r * K + k0 + scol),
          (__attribute__((address_space(3))) void*)(As + rbase * BK), 16, 0, 0);
      __builtin_amdgcn_global_load_lds(
          (const __attribute__((address_space(1))) void*)(Bg + (size_t)r * K + k0 + scol),
          (__attribute__((address_space(3))) void*)(Bs + rbase * BK), 16, 0, 0);
    }
    __syncthreads();

    const bf16x8* Asv = reinterpret_cast<const bf16x8*>(As);
    const bf16x8* Bsv = reinterpret_cast<const bf16x8*>(Bs);
    bf16x8 af[4], bfr[4];
#pragma unroll
    for (int mf = 0; mf < 4; mf++)
      af[mf] = Asv[(wm * 64 + mf * 16 + l15) * 4 + l4];
#pragma unroll
    for (int nf = 0; nf < 4; nf++)
      bfr[nf] = Bsv[(wn * 64 + nf * 16 + l15) * 4 + l4];
#pragma unroll
    for (int mf = 0; mf < 4; mf++)
#pragma unroll
      for (int nf = 0; nf < 4; nf++)
        acc[mf][nf] = __builtin_amdgcn_mfma_f32_16x16x32_bf16(af[mf], bfr[nf], acc[mf][nf], 0, 0, 0);
    __syncthreads();
  }

#pragma unroll
  for (int mf = 0; mf < 4; mf++)
#pragma unroll
    for (int nf = 0; nf < 4; nf++)
#pragma unroll
      for (int i = 0; i < 4; i++) {
        int row = bm + wm * 64 + mf * 16 + l4 * 4 + i;
        int col = bn + wn * 64 + nf * 16 + l15;
        size_t idx = (size_t)row * Ndim + col;
        float val = acc[mf][nf][i];
        if (OUT_MODE == 0) {
          ((float*)Cout)[idx] = val;
        } else if (OUT_MODE == 1) {
          ((bf16_t*)Cout)[idx] = (bf16_t)val;
        } else {
          ((float*)Cout)[idx] = val + resid[idx];
        }
      }
}

// ---------------------------------------------------------------------------
// Gates kernel: one block per (b,t) row. Stage the 34KB logits row in LDS,
// compute 64x16 softmax-17s, REWRITE the row in place as gates:
//   per h (272 slots): A[i][j] bf16 at h*272 + i*16 + j (j=softmax out 1..16),
//                      u[i] = a0*v bf16 at h*272 + 256 + i.
// Safe in-place: block reads only its own row (via LDS), then overwrites it.
// ---------------------------------------------------------------------------
__global__ __launch_bounds__(256) void gates_kernel(bf16_t* __restrict__ lg,
                                                    const float* __restrict__ v) {
  int row = blockIdx.x;            // b*1024 + t
  __shared__ bf16_t Ls[NA];        // 34816 B
  size_t Rb = (size_t)row * NA;

  // stage row (coalesced bf16x8)
  {
    const bf16x8* src = reinterpret_cast<const bf16x8*>(lg + Rb);
    bf16x8* dst = reinterpret_cast<bf16x8*>(Ls);
    for (int idx = threadIdx.x; idx < NA / 8; idx += 256) dst[idx] = src[idx];
  }
  __syncthreads();

  int h = threadIdx.x >> 2;            // 0..63
  int i0 = (threadIdx.x & 3) * 4;      // 0,4,8,12

  float4 vv = *reinterpret_cast<const float4*>(v + (size_t)row * D_DIM + h * 16 + i0);
  float vl[4] = {vv.x, vv.y, vv.z, vv.w};

  bf16_t* Arow = lg + Rb + h * 272;

#pragma unroll
  for (int r = 0; r < 4; ++r) {
    int i = i0 + r;
    const bf16_t* lrow = Ls + h * 272 + i * 17;
    float e[17];
    float mx = -1e30f;
#pragma unroll
    for (int j = 0; j < 17; ++j) {
      e[j] = (float)lrow[j];
      mx = fmaxf(mx, e[j]);
    }
    float s = 0.f;
#pragma unroll
    for (int j = 0; j < 17; ++j) {
      e[j] = __expf(e[j] - mx);
      s += e[j];
    }
    float inv = 1.0f / s;
    bf16x8 w0, w1;
#pragma unroll
    for (int j = 0; j < 8; ++j) w0[j] = (bf16_t)(e[1 + j] * inv);
#pragma unroll
    for (int j = 0; j < 8; ++j) w1[j] = (bf16_t)(e[9 + j] * inv);
    *reinterpret_cast<bf16x8*>(Arow + i * 16) = w0;
    *reinterpret_cast<bf16x8*>(Arow + i * 16 + 8) = w1;
    Arow[256 + i] = (bf16_t)(e[0] * inv * vl[r]);
  }
}

// ---------------------------------------------------------------------------
// Scan kernel: one block (256 thr = 4 waves) per chain (b,h).
//   Waves 0-2: copy next chunk's gates (global, 544 B per t) into f32 LDS
//              (A padded stride-20 words -> ~conflict-free; u plain).
//   Wave 3:    sequential recurrence, state in SGPRs via readlane.
// Chunk = 32 timesteps, double-buffered (86 KB LDS).
// ---------------------------------------------------------------------------
#define SCT 32
#define NSC (T_DIM / SCT)

__global__ __launch_bounds__(256) void scan_kernel(const bf16_t* __restrict__ lg,
                                                   bf16_t* __restrict__ y) {
  int chain = blockIdx.x;           // 0..255
  int b = chain >> 6;
  int hh = chain & 63;

  __shared__ float Af[2][SCT * 320];   // 81920 B (stride 20 f32 per row of 16)
  __shared__ float Uf[2][SCT * 16];    //  4096 B

  int tid = threadIdx.x;
  int lane = tid & 63;
  int w = tid >> 6;                 // 0..3; 3 = scanner

  auto copy_chunk = [&](int c, int buf) {
    int r = lane;                   // 0..63; only r<34 active
    if (r < 34) {
      for (int tl = w; tl < SCT; tl += 3) {
        size_t gbase = ((size_t)(b * T_DIM + c * SCT + tl)) * NA + hh * 272;
        bf16x8 d = *reinterpret_cast<const bf16x8*>(lg + gbase + r * 8);
        float f[8];
#pragma unroll
        for (int q = 0; q < 8; ++q) f[q] = (float)d[q];
        if (r < 32) {
          int i = r >> 1, hf = r & 1;
          float* p = &Af[buf][tl * 320 + i * 20 + hf * 8];
          *reinterpret_cast<f32x4*>(p)     = (f32x4){f[0], f[1], f[2], f[3]};
          *reinterpret_cast<f32x4*>(p + 4) = (f32x4){f[4], f[5], f[6], f[7]};
        } else {
          int hf = r - 32;
          float* p = &Uf[buf][tl * 16 + hf * 8];
          *reinterpret_cast<f32x4*>(p)     = (f32x4){f[0], f[1], f[2], f[3]};
          *reinterpret_cast<f32x4*>(p + 4) = (f32x4){f[4], f[5], f[6], f[7]};
        }
      }
    }
  };

  if (w < 3) copy_chunk(0, 0);
  __syncthreads();

  float s0v[16];
#pragma unroll
  for (int j = 0; j < 16; ++j) s0v[j] = 0.f;

  int i16 = lane & 15;

  for (int c = 0; c < NSC; ++c) {
    int buf = c & 1;
    if (w < 3) {
      if (c + 1 < NSC) copy_chunk(c + 1, buf ^ 1);
    } else {
      const float* Ab = Af[buf];
      const float* ub = Uf[buf];
      bf16_t* yp = y + ((size_t)(b * T_DIM + c * SCT)) * D_DIM + hh * 16 + i16;

      f32x4 a0 = *reinterpret_cast<const f32x4*>(&Ab[i16 * 20 + 0]);
      f32x4 a1 = *reinterpret_cast<const f32x4*>(&Ab[i16 * 20 + 4]);
      f32x4 a2 = *reinterpret_cast<const f32x4*>(&Ab[i16 * 20 + 8]);
      f32x4 a3 = *reinterpret_cast<const f32x4*>(&Ab[i16 * 20 + 12]);
      float uu = ub[i16];

#pragma unroll 2
      for (int t = 0; t < SCT; ++t) {
        int tn = (t < SCT - 1) ? t + 1 : t;
        const float* An = Ab + tn * 320;
        f32x4 b0 = *reinterpret_cast<const f32x4*>(&An[i16 * 20 + 0]);
        f32x4 b1 = *reinterpret_cast<const f32x4*>(&An[i16 * 20 + 4]);
        f32x4 b2 = *reinterpret_cast<const f32x4*>(&An[i16 * 20 + 8]);
        f32x4 b3 = *reinterpret_cast<const f32x4*>(&An[i16 * 20 + 12]);
        float un = ub[tn * 16 + i16];

        // 4 parallel fma chains (u seeds chain 0)
        float q0 = fmaf(a0[0], s0v[0], uu);
        q0 = fmaf(a0[1], s0v[1], q0);
        q0 = fmaf(a0[2], s0v[2], q0);
        q0 = fmaf(a0[3], s0v[3], q0);
        float q1 = fmaf(a1[1], s0v[5], a1[0] * s0v[4]);
        q1 = fmaf(a1[2], s0v[6], q1);
        q1 = fmaf(a1[3], s0v[7], q1);
        float q2 = fmaf(a2[1], s0v[9], a2[0] * s0v[8]);
        q2 = fmaf(a2[2], s0v[10], q2);
        q2 = fmaf(a2[3], s0v[11], q2);
        float q3 = fmaf(a3[1], s0v[13], a3[0] * s0v[12]);
        q3 = fmaf(a3[2], s0v[14], q3);
        q3 = fmaf(a3[3], s0v[15], q3);
        float p = (q0 + q1) + (q2 + q3);

        if (lane < 16) yp[(size_t)t * D_DIM] = (bf16_t)p;

        // broadcast new state into wave-uniform registers
#pragma unroll
        for (int j = 0; j < 16; ++j)
          s0v[j] = __uint_as_float(__builtin_amdgcn_readlane(__float_as_uint(p), j));

        a0 = b0; a1 = b1; a2 = b2; a3 = b3; uu = un;
      }
    }
    __syncthreads();
  }
}

// ---------------------------------------------------------------------------
extern "C" void kernel_launch(void* const* d_in, const int* in_sizes, int n_in,
                              void* d_out, int out_size, void* d_ws, size_t ws_size,
                              hipStream_t stream) {
  const float* x      = (const float*)d_in[0];
  const float* norm_w = (const float*)d_in[1];
  const float* W_v    = (const float*)d_in[2];
  const float* W_a    = (const float*)d_in[3];
  const float* W_out  = (const float*)d_in[4];

  char* ws = (char*)d_ws;
  size_t off = 0;
  auto alloc = [&](size_t bytes) {
    void* p = ws + off;
    off += (bytes + 255) & ~(size_t)255;
    return p;
  };
  bf16_t* wv_b = (bf16_t*)alloc((size_t)D_DIM * D_DIM * 2);        // 2 MB
  bf16_t* wa_b = (bf16_t*)alloc((size_t)NA * D_DIM * 2);           // 35.7 MB
  bf16_t* wo_b = (bf16_t*)alloc((size_t)D_DIM * D_DIM * 2);        // 2 MB
  bf16_t* h_b  = (bf16_t*)alloc((size_t)NT * D_DIM * 2);           // 8 MB
  float*  v_f  = (float*)alloc((size_t)NT * D_DIM * 4);            // 16 MB
  bf16_t* lg_b = (bf16_t*)alloc((size_t)NT * NA * 2);              // 142.6 MB
  bf16_t* y_b  = (bf16_t*)alloc((size_t)NT * D_DIM * 2);           // 8 MB

  cvt_kernel<<<1024, 256, 0, stream>>>(W_v, wv_b, D_DIM * D_DIM / 4);
  cvt_kernel<<<1024, 256, 0, stream>>>(W_a, wa_b, NA * D_DIM / 4);
  cvt_kernel<<<1024, 256, 0, stream>>>(W_out, wo_b, D_DIM * D_DIM / 4);

  rmsnorm_kernel<<<NT, 256, 0, stream>>>(x, norm_w, h_b);

  gemm_nt_kernel<0><<<dim3(NT / 128, D_DIM / 128), 256, 0, stream>>>(
      h_b, wv_b, (void*)v_f, nullptr, NT, D_DIM, D_DIM);

  gemm_nt_kernel<1><<<dim3(NT / 128, NA / 128), 256, 0, stream>>>(
      h_b, wa_b, (void*)lg_b, nullptr, NT, NA, D_DIM);

  gates_kernel<<<NT, 256, 0, stream>>>(lg_b, v_f);

  scan_kernel<<<256, 256, 0, stream>>>(lg_b, y_b);

  gemm_nt_kernel<2><<<dim3(NT / 128, D_DIM / 128), 256, 0, stream>>>(
      y_b, wo_b, d_out, x, NT, D_DIM, D_DIM);
}

// Round 5
// 392.477 us; speedup vs baseline: 1.2453x; 1.2453x over previous
//
#include <hip/hip_runtime.h>
#include <hip/hip_bf16.h>
#include <math.h>

// Problem constants
#define B_DIM 4
#define T_DIM 1024
#define D_DIM 1024
#define M_DIM 16
#define H_DIM 64
#define NT    4096            // B*T
#define NA    17408           // H*M*(M+1)
#define EPSV  1e-5f
#define CL    16              // scan chunk length
#define NC    64              // chunks per chain (T/CL)

typedef __bf16 bf16_t;
typedef __bf16 bf16x4 __attribute__((ext_vector_type(4)));
typedef __bf16 bf16x8 __attribute__((ext_vector_type(8)));
typedef float  f32x4  __attribute__((ext_vector_type(4)));

// ---------------------------------------------------------------------------
// fp32 -> bf16 conversion
// ---------------------------------------------------------------------------
__global__ __launch_bounds__(256) void cvt_kernel(const float* __restrict__ in,
                                                  bf16_t* __restrict__ out, int n4) {
  int idx = blockIdx.x * blockDim.x + threadIdx.x;
  int stride = gridDim.x * blockDim.x;
  for (; idx < n4; idx += stride) {
    float4 v = reinterpret_cast<const float4*>(in)[idx];
    bf16x4 o;
    o[0] = (bf16_t)v.x; o[1] = (bf16_t)v.y; o[2] = (bf16_t)v.z; o[3] = (bf16_t)v.w;
    reinterpret_cast<bf16x4*>(out)[idx] = o;
  }
}

// ---------------------------------------------------------------------------
// RMSNorm
// ---------------------------------------------------------------------------
__global__ __launch_bounds__(256) void rmsnorm_kernel(const float* __restrict__ x,
                                                      const float* __restrict__ w,
                                                      bf16_t* __restrict__ h) {
  int row = blockIdx.x;
  int tid = threadIdx.x;
  const float4* xr = reinterpret_cast<const float4*>(x + (size_t)row * D_DIM);
  float4 xv = xr[tid];
  float ss = xv.x * xv.x + xv.y * xv.y + xv.z * xv.z + xv.w * xv.w;
#pragma unroll
  for (int m = 1; m < 64; m <<= 1) ss += __shfl_xor(ss, m, 64);
  __shared__ float red[4];
  int lane = tid & 63, wid = tid >> 6;
  if (lane == 0) red[wid] = ss;
  __syncthreads();
  float tot = red[0] + red[1] + red[2] + red[3];
  float scale = rsqrtf(tot * (1.0f / D_DIM) + EPSV);
  float4 wv = reinterpret_cast<const float4*>(w)[tid];
  bf16x4 o;
  o[0] = (bf16_t)(xv.x * scale * wv.x);
  o[1] = (bf16_t)(xv.y * scale * wv.y);
  o[2] = (bf16_t)(xv.z * scale * wv.z);
  o[3] = (bf16_t)(xv.w * scale * wv.w);
  reinterpret_cast<bf16x4*>(h)[(size_t)row * 256 + tid] = o;
}

// ---------------------------------------------------------------------------
// NT GEMM: 128x128 tile, BK=32 (R1 known-good structure)
// OUT_MODE: 0 = f32 out, 1 = bf16 out, 2 = f32 out + residual add
// ---------------------------------------------------------------------------
template <int OUT_MODE>
__global__ __launch_bounds__(256) void gemm_nt_kernel(const bf16_t* __restrict__ A,
                                                      const bf16_t* __restrict__ Bw,
                                                      void* __restrict__ Cout,
                                                      const float* __restrict__ resid,
                                                      int Mdim, int Ndim, int K) {
  constexpr int BM = 128, BN = 128, BK = 32;
  __shared__ bf16_t As[BM * BK];
  __shared__ bf16_t Bs[BN * BK];

  int tid = threadIdx.x;
  int lane = tid & 63;
  int wid = tid >> 6;
  int wm = wid >> 1, wn = wid & 1;
  int bm = blockIdx.x * BM;
  int bn = blockIdx.y * BN;
  int l15 = lane & 15;
  int l4 = lane >> 4;

  f32x4 acc[4][4];
#pragma unroll
  for (int i = 0; i < 4; i++)
#pragma unroll
    for (int j = 0; j < 4; j++) acc[i][j] = (f32x4){0.f, 0.f, 0.f, 0.f};

  const bf16_t* Ag = A + (size_t)bm * K;
  const bf16_t* Bg = Bw + (size_t)bn * K;
  int srow_lane = lane >> 2;
  int scol = (lane & 3) * 8;

  for (int k0 = 0; k0 < K; k0 += BK) {
#pragma unroll
    for (int i = 0; i < 2; i++) {
      int rbase = wid * 32 + i * 16;
      int r = rbase + srow_lane;
      __builtin_amdgcn_global_load_lds(
          (const __attribute__((address_space(1))) void*)(Ag + (size_t)r * K + k0 + scol),
          (__attribute__((address_space(3))) void*)(As + rbase * BK), 16, 0, 0);
      __builtin_amdgcn_global_load_lds(
          (const __attribute__((address_space(1))) void*)(Bg + (size_t)r * K + k0 + scol),
          (__attribute__((address_space(3))) void*)(Bs + rbase * BK), 16, 0, 0);
    }
    __syncthreads();

    const bf16x8* Asv = reinterpret_cast<const bf16x8*>(As);
    const bf16x8* Bsv = reinterpret_cast<const bf16x8*>(Bs);
    bf16x8 af[4], bfr[4];
#pragma unroll
    for (int mf = 0; mf < 4; mf++)
      af[mf] = Asv[(wm * 64 + mf * 16 + l15) * 4 + l4];
#pragma unroll
    for (int nf = 0; nf < 4; nf++)
      bfr[nf] = Bsv[(wn * 64 + nf * 16 + l15) * 4 + l4];
#pragma unroll
    for (int mf = 0; mf < 4; mf++)
#pragma unroll
      for (int nf = 0; nf < 4; nf++)
        acc[mf][nf] = __builtin_amdgcn_mfma_f32_16x16x32_bf16(af[mf], bfr[nf], acc[mf][nf], 0, 0, 0);
    __syncthreads();
  }

#pragma unroll
  for (int mf = 0; mf < 4; mf++)
#pragma unroll
    for (int nf = 0; nf < 4; nf++)
#pragma unroll
      for (int i = 0; i < 4; i++) {
        int row = bm + wm * 64 + mf * 16 + l4 * 4 + i;
        int col = bn + wn * 64 + nf * 16 + l15;
        size_t idx = (size_t)row * Ndim + col;
        float val = acc[mf][nf][i];
        if (OUT_MODE == 0) {
          ((float*)Cout)[idx] = val;
        } else if (OUT_MODE == 1) {
          ((bf16_t*)Cout)[idx] = (bf16_t)val;
        } else {
          ((float*)Cout)[idx] = val + resid[idx];
        }
      }
}

// ---------------------------------------------------------------------------
// In-lane softmax over 17 logits; returns gate rows (a[0..3] = A[i][0..15])
// and u = gates[0] * vval.
// ---------------------------------------------------------------------------
__device__ __forceinline__ void softmax17(const bf16_t* __restrict__ lp, float vval,
                                          f32x4& a0, f32x4& a1, f32x4& a2, f32x4& a3,
                                          float& u) {
  float e[17];
  float mx = -1e30f;
#pragma unroll
  for (int j = 0; j < 17; ++j) {
    e[j] = (float)lp[j];
    mx = fmaxf(mx, e[j]);
  }
  float s = 0.f;
#pragma unroll
  for (int j = 0; j < 17; ++j) {
    e[j] = __expf(e[j] - mx);
    s += e[j];
  }
  float inv = 1.0f / s;
  a0 = (f32x4){e[1] * inv, e[2] * inv, e[3] * inv, e[4] * inv};
  a1 = (f32x4){e[5] * inv, e[6] * inv, e[7] * inv, e[8] * inv};
  a2 = (f32x4){e[9] * inv, e[10] * inv, e[11] * inv, e[12] * inv};
  a3 = (f32x4){e[13] * inv, e[14] * inv, e[15] * inv, e[16] * inv};
  u = e[0] * inv * vval;
}

// ---------------------------------------------------------------------------
// scanA: per (chain, chunk) instance compute chunk summary (P, q):
//   s_out = P s_in + q for the 16-step chunk.
// 16-lane group per instance; lane i owns row i of suffix product R and q_i.
// Iterate tau = 15..0:  q += R*u_tau ; R <- R*A_tau.
// A_tau rows shared via LDS (uniform broadcast reads).
// grid: (256 = b*NC+c, 4 = h-group), block 256 (16 groups of 16 lanes).
// summary layout: [inst][272]: P row-major at [i*16+k], q at [256+i].
// ---------------------------------------------------------------------------
__global__ __launch_bounds__(256) void scanA_kernel(const bf16_t* __restrict__ lg,
                                                    const float* __restrict__ v,
                                                    float* __restrict__ sum) {
  int bc = blockIdx.x;
  int b = bc >> 6;
  int c = bc & 63;
  int g = threadIdx.x >> 4;
  int i = threadIdx.x & 15;
  int h = blockIdx.y * 16 + g;
  int chain = b * 64 + h;

  __shared__ float Arows[16][16][16];  // [group][k][k']
  __shared__ float Us[16][16];         // [group][k]

  // R = identity row i
  f32x4 R0 = (f32x4){i == 0 ? 1.f : 0.f, i == 1 ? 1.f : 0.f, i == 2 ? 1.f : 0.f, i == 3 ? 1.f : 0.f};
  f32x4 R1 = (f32x4){i == 4 ? 1.f : 0.f, i == 5 ? 1.f : 0.f, i == 6 ? 1.f : 0.f, i == 7 ? 1.f : 0.f};
  f32x4 R2 = (f32x4){i == 8 ? 1.f : 0.f, i == 9 ? 1.f : 0.f, i == 10 ? 1.f : 0.f, i == 11 ? 1.f : 0.f};
  f32x4 R3 = (f32x4){i == 12 ? 1.f : 0.f, i == 13 ? 1.f : 0.f, i == 14 ? 1.f : 0.f, i == 15 ? 1.f : 0.f};
  float q = 0.f;

#pragma unroll 1
  for (int tau = CL - 1; tau >= 0; --tau) {
    int r = b * T_DIM + c * CL + tau;
    const bf16_t* lp = lg + (size_t)r * NA + h * 272 + i * 17;
    float vval = v[(size_t)r * D_DIM + h * 16 + i];
    f32x4 a0, a1, a2, a3;
    float uu;
    softmax17(lp, vval, a0, a1, a2, a3, uu);

    *reinterpret_cast<f32x4*>(&Arows[g][i][0]) = a0;
    *reinterpret_cast<f32x4*>(&Arows[g][i][4]) = a1;
    *reinterpret_cast<f32x4*>(&Arows[g][i][8]) = a2;
    *reinterpret_cast<f32x4*>(&Arows[g][i][12]) = a3;
    Us[g][i] = uu;
    asm volatile("s_waitcnt lgkmcnt(0)" ::: "memory");
    __builtin_amdgcn_sched_barrier(0);

    // q += R * u_tau
    f32x4 u0 = *reinterpret_cast<const f32x4*>(&Us[g][0]);
    f32x4 u1 = *reinterpret_cast<const f32x4*>(&Us[g][4]);
    f32x4 u2 = *reinterpret_cast<const f32x4*>(&Us[g][8]);
    f32x4 u3 = *reinterpret_cast<const f32x4*>(&Us[g][12]);
    float qa = fmaf(R0[0], u0[0], fmaf(R0[1], u0[1], fmaf(R0[2], u0[2], R0[3] * u0[3])));
    float qb = fmaf(R1[0], u1[0], fmaf(R1[1], u1[1], fmaf(R1[2], u1[2], R1[3] * u1[3])));
    float qc = fmaf(R2[0], u2[0], fmaf(R2[1], u2[1], fmaf(R2[2], u2[2], R2[3] * u2[3])));
    float qd = fmaf(R3[0], u3[0], fmaf(R3[1], u3[1], fmaf(R3[2], u3[2], R3[3] * u3[3])));
    q += (qa + qb) + (qc + qd);

    // R <- R * A_tau  : Rn[k'] = sum_k R[k] * Arows[k][k']
    f32x4 n0 = (f32x4){0.f, 0.f, 0.f, 0.f}, n1 = n0, n2 = n0, n3 = n0;
#pragma unroll
    for (int k = 0; k < 16; ++k) {
      float rk = (k < 4) ? R0[k & 3] : (k < 8) ? R1[k & 3] : (k < 12) ? R2[k & 3] : R3[k & 3];
      f32x4 b0 = *reinterpret_cast<const f32x4*>(&Arows[g][k][0]);
      f32x4 b1 = *reinterpret_cast<const f32x4*>(&Arows[g][k][4]);
      f32x4 b2 = *reinterpret_cast<const f32x4*>(&Arows[g][k][8]);
      f32x4 b3 = *reinterpret_cast<const f32x4*>(&Arows[g][k][12]);
#pragma unroll
      for (int e2 = 0; e2 < 4; ++e2) {
        n0[e2] = fmaf(rk, b0[e2], n0[e2]);
        n1[e2] = fmaf(rk, b1[e2], n1[e2]);
        n2[e2] = fmaf(rk, b2[e2], n2[e2]);
        n3[e2] = fmaf(rk, b3[e2], n3[e2]);
      }
    }
    R0 = n0; R1 = n1; R2 = n2; R3 = n3;
    // in-wave LDS FIFO ordering makes next-step overwrite safe (reads issued first)
  }

  float* sp = sum + (size_t)(chain * NC + c) * 272;
  *reinterpret_cast<f32x4*>(&sp[i * 16 + 0]) = R0;
  *reinterpret_cast<f32x4*>(&sp[i * 16 + 4]) = R1;
  *reinterpret_cast<f32x4*>(&sp[i * 16 + 8]) = R2;
  *reinterpret_cast<f32x4*>(&sp[i * 16 + 12]) = R3;
  sp[256 + i] = q;
}

// ---------------------------------------------------------------------------
// scanB: serial scan over 64 chunk summaries per chain.
// 256 blocks x 64 threads (1 wave). LDS double-buffered segments of 8 chunks
// staged via global_load_lds (counted prefetch, vmcnt before consume).
// Writes s_init[chain][c][16] = state at chunk START.
// ---------------------------------------------------------------------------
__global__ __launch_bounds__(64) void scanB_kernel(const float* __restrict__ sum,
                                                   float* __restrict__ sinit) {
  int chain = blockIdx.x;
  int lane = threadIdx.x;
  int i = lane & 15;

  __shared__ float seg[2][2176];   // 8 chunks * 272 f32

  const float* gbase = sum + (size_t)chain * NC * 272;

  auto load_seg = [&](int s, int buf) {
#pragma unroll
    for (int r = 0; r < 9; ++r) {
      int idx = r * 256 + lane * 4;
      if (idx < 2176) {
        __builtin_amdgcn_global_load_lds(
            (const __attribute__((address_space(1))) void*)(gbase + (size_t)s * 2176 + idx),
            (__attribute__((address_space(3))) void*)(&seg[buf][r * 256]), 16, 0, 0);
      }
    }
  };

  load_seg(0, 0);
  asm volatile("s_waitcnt vmcnt(0)" ::: "memory");
  __builtin_amdgcn_sched_barrier(0);

  f32x4 S0 = (f32x4){0.f, 0.f, 0.f, 0.f}, S1 = S0, S2 = S0, S3 = S0;
  float own = 0.f;

  for (int sg = 0; sg < 8; ++sg) {
    int buf = sg & 1;
    if (sg + 1 < 8) load_seg(sg + 1, buf ^ 1);
#pragma unroll 1
    for (int cc = 0; cc < 8; ++cc) {
      int c = sg * 8 + cc;
      const float* Pb = &seg[buf][cc * 272];
      if (lane < 16) sinit[(size_t)(chain * NC + c) * 16 + i] = own;

      f32x4 p0 = *reinterpret_cast<const f32x4*>(&Pb[i * 16 + 0]);
      f32x4 p1 = *reinterpret_cast<const f32x4*>(&Pb[i * 16 + 4]);
      f32x4 p2 = *reinterpret_cast<const f32x4*>(&Pb[i * 16 + 8]);
      f32x4 p3 = *reinterpret_cast<const f32x4*>(&Pb[i * 16 + 12]);
      float qq = Pb[256 + i];

      float pa = fmaf(p0[0], S0[0], fmaf(p0[1], S0[1], fmaf(p0[2], S0[2], p0[3] * S0[3])));
      float pb = fmaf(p1[0], S1[0], fmaf(p1[1], S1[1], fmaf(p1[2], S1[2], p1[3] * S1[3])));
      float pc = fmaf(p2[0], S2[0], fmaf(p2[1], S2[1], fmaf(p2[2], S2[2], p2[3] * S2[3])));
      float pd = fmaf(p3[0], S3[0], fmaf(p3[1], S3[1], fmaf(p3[2], S3[2], p3[3] * S3[3])));
      float p = (pa + pb) + (pc + pd) + qq;
      own = p;

#pragma unroll
      for (int j = 0; j < 4; ++j) {
        S0[j] = __shfl(p, j, 64);
        S1[j] = __shfl(p, 4 + j, 64);
        S2[j] = __shfl(p, 8 + j, 64);
        S3[j] = __shfl(p, 12 + j, 64);
      }
    }
    if (sg + 1 < 8) {
      asm volatile("s_waitcnt vmcnt(0)" ::: "memory");
      __builtin_amdgcn_sched_barrier(0);
    }
  }
}

// ---------------------------------------------------------------------------
// scanC: re-run each chunk from its s_init, writing y. 16-lane group per
// instance; lane i keeps its own gate row (from its softmax) in registers;
// state replicated per lane, re-broadcast each step via in-group LDS bounce.
// ---------------------------------------------------------------------------
__global__ __launch_bounds__(256) void scanC_kernel(const bf16_t* __restrict__ lg,
                                                    const float* __restrict__ v,
                                                    const float* __restrict__ sinit,
                                                    bf16_t* __restrict__ y) {
  int bc = blockIdx.x;
  int b = bc >> 6;
  int c = bc & 63;
  int g = threadIdx.x >> 4;
  int i = threadIdx.x & 15;
  int h = blockIdx.y * 16 + g;
  int chain = b * 64 + h;

  __shared__ float Sb[16][16];

  const float* ip = sinit + (size_t)(chain * NC + c) * 16;
  f32x4 S0 = *reinterpret_cast<const f32x4*>(&ip[0]);
  f32x4 S1 = *reinterpret_cast<const f32x4*>(&ip[4]);
  f32x4 S2 = *reinterpret_cast<const f32x4*>(&ip[8]);
  f32x4 S3 = *reinterpret_cast<const f32x4*>(&ip[12]);

#pragma unroll 1
  for (int t = 0; t < CL; ++t) {
    int r = b * T_DIM + c * CL + t;
    const bf16_t* lp = lg + (size_t)r * NA + h * 272 + i * 17;
    float vval = v[(size_t)r * D_DIM + h * 16 + i];
    f32x4 a0, a1, a2, a3;
    float uu;
    softmax17(lp, vval, a0, a1, a2, a3, uu);

    float pa = fmaf(a0[0], S0[0], fmaf(a0[1], S0[1], fmaf(a0[2], S0[2], a0[3] * S0[3])));
    float pb = fmaf(a1[0], S1[0], fmaf(a1[1], S1[1], fmaf(a1[2], S1[2], a1[3] * S1[3])));
    float pc = fmaf(a2[0], S2[0], fmaf(a2[1], S2[1], fmaf(a2[2], S2[2], a2[3] * S2[3])));
    float pd = fmaf(a3[0], S3[0], fmaf(a3[1], S3[1], fmaf(a3[2], S3[2], a3[3] * S3[3])));
    float p = (pa + pb) + (pc + pd) + uu;

    y[(size_t)r * D_DIM + h * 16 + i] = (bf16_t)p;

    Sb[g][i] = p;
    asm volatile("s_waitcnt lgkmcnt(0)" ::: "memory");
    __builtin_amdgcn_sched_barrier(0);
    S0 = *reinterpret_cast<const f32x4*>(&Sb[g][0]);
    S1 = *reinterpret_cast<const f32x4*>(&Sb[g][4]);
    S2 = *reinterpret_cast<const f32x4*>(&Sb[g][8]);
    S3 = *reinterpret_cast<const f32x4*>(&Sb[g][12]);
  }
}

// ---------------------------------------------------------------------------
extern "C" void kernel_launch(void* const* d_in, const int* in_sizes, int n_in,
                              void* d_out, int out_size, void* d_ws, size_t ws_size,
                              hipStream_t stream) {
  const float* x      = (const float*)d_in[0];
  const float* norm_w = (const float*)d_in[1];
  const float* W_v    = (const float*)d_in[2];
  const float* W_a    = (const float*)d_in[3];
  const float* W_out  = (const float*)d_in[4];

  char* ws = (char*)d_ws;
  size_t off = 0;
  auto alloc = [&](size_t bytes) {
    void* p = ws + off;
    off += (bytes + 255) & ~(size_t)255;
    return p;
  };
  bf16_t* wv_b = (bf16_t*)alloc((size_t)D_DIM * D_DIM * 2);        // 2 MB
  bf16_t* wa_b = (bf16_t*)alloc((size_t)NA * D_DIM * 2);           // 35.7 MB
  bf16_t* wo_b = (bf16_t*)alloc((size_t)D_DIM * D_DIM * 2);        // 2 MB
  bf16_t* h_b  = (bf16_t*)alloc((size_t)NT * D_DIM * 2);           // 8 MB
  float*  v_f  = (float*)alloc((size_t)NT * D_DIM * 4);            // 16 MB
  bf16_t* lg_b = (bf16_t*)alloc((size_t)NT * NA * 2);              // 142.6 MB
  bf16_t* y_b  = (bf16_t*)alloc((size_t)NT * D_DIM * 2);           // 8 MB
  float*  sum_f   = (float*)alloc((size_t)256 * NC * 272 * 4);     // 17.8 MB
  float*  sinit_f = (float*)alloc((size_t)256 * NC * 16 * 4);      // 1.05 MB

  cvt_kernel<<<1024, 256, 0, stream>>>(W_v, wv_b, D_DIM * D_DIM / 4);
  cvt_kernel<<<1024, 256, 0, stream>>>(W_a, wa_b, NA * D_DIM / 4);
  cvt_kernel<<<1024, 256, 0, stream>>>(W_out, wo_b, D_DIM * D_DIM / 4);

  rmsnorm_kernel<<<NT, 256, 0, stream>>>(x, norm_w, h_b);

  gemm_nt_kernel<0><<<dim3(NT / 128, D_DIM / 128), 256, 0, stream>>>(
      h_b, wv_b, (void*)v_f, nullptr, NT, D_DIM, D_DIM);

  gemm_nt_kernel<1><<<dim3(NT / 128, NA / 128), 256, 0, stream>>>(
      h_b, wa_b, (void*)lg_b, nullptr, NT, NA, D_DIM);

  scanA_kernel<<<dim3(256, 4), 256, 0, stream>>>(lg_b, v_f, sum_f);
  scanB_kernel<<<256, 64, 0, stream>>>(sum_f, sinit_f);
  scanC_kernel<<<dim3(256, 4), 256, 0, stream>>>(lg_b, v_f, sinit_f, y_b);

  gemm_nt_kernel<2><<<dim3(NT / 128, D_DIM / 128), 256, 0, stream>>>(
      y_b, wo_b, d_out, x, NT, D_DIM, D_DIM);
}

// Round 6
// 366.050 us; speedup vs baseline: 1.3352x; 1.0722x over previous
//
#include <hip/hip_runtime.h>
#include <hip/hip_bf16.h>
#include <math.h>

// Problem constants
#define B_DIM 4
#define T_DIM 1024
#define D_DIM 1024
#define M_DIM 16
#define H_DIM 64
#define NT    4096            // B*T
#define NA    17408           // H*M*(M+1)
#define EPSV  1e-5f
#define CL    16              // scan chunk length
#define NC    64              // chunks per chain (T/CL)

typedef __bf16 bf16_t;
typedef __bf16 bf16x4 __attribute__((ext_vector_type(4)));
typedef __bf16 bf16x8 __attribute__((ext_vector_type(8)));
typedef float  f32x4  __attribute__((ext_vector_type(4)));

#define PBAR() do { asm volatile("" ::: "memory"); __builtin_amdgcn_s_barrier(); asm volatile("" ::: "memory"); } while (0)

// ---------------------------------------------------------------------------
// fp32 -> bf16 conversion
// ---------------------------------------------------------------------------
__global__ __launch_bounds__(256) void cvt_kernel(const float* __restrict__ in,
                                                  bf16_t* __restrict__ out, int n4) {
  int idx = blockIdx.x * blockDim.x + threadIdx.x;
  int stride = gridDim.x * blockDim.x;
  for (; idx < n4; idx += stride) {
    float4 v = reinterpret_cast<const float4*>(in)[idx];
    bf16x4 o;
    o[0] = (bf16_t)v.x; o[1] = (bf16_t)v.y; o[2] = (bf16_t)v.z; o[3] = (bf16_t)v.w;
    reinterpret_cast<bf16x4*>(out)[idx] = o;
  }
}

// ---------------------------------------------------------------------------
// RMSNorm
// ---------------------------------------------------------------------------
__global__ __launch_bounds__(256) void rmsnorm_kernel(const float* __restrict__ x,
                                                      const float* __restrict__ w,
                                                      bf16_t* __restrict__ h) {
  int row = blockIdx.x;
  int tid = threadIdx.x;
  const float4* xr = reinterpret_cast<const float4*>(x + (size_t)row * D_DIM);
  float4 xv = xr[tid];
  float ss = xv.x * xv.x + xv.y * xv.y + xv.z * xv.z + xv.w * xv.w;
#pragma unroll
  for (int m = 1; m < 64; m <<= 1) ss += __shfl_xor(ss, m, 64);
  __shared__ float red[4];
  int lane = tid & 63, wid = tid >> 6;
  if (lane == 0) red[wid] = ss;
  __syncthreads();
  float tot = red[0] + red[1] + red[2] + red[3];
  float scale = rsqrtf(tot * (1.0f / D_DIM) + EPSV);
  float4 wv = reinterpret_cast<const float4*>(w)[tid];
  bf16x4 o;
  o[0] = (bf16_t)(xv.x * scale * wv.x);
  o[1] = (bf16_t)(xv.y * scale * wv.y);
  o[2] = (bf16_t)(xv.z * scale * wv.z);
  o[3] = (bf16_t)(xv.w * scale * wv.w);
  reinterpret_cast<bf16x4*>(h)[(size_t)row * 256 + tid] = o;
}

// ---------------------------------------------------------------------------
// Small NT GEMM: 128x128 tile, BK=32 (known-good) for the two D x D GEMMs.
// OUT_MODE: 0 = f32 out, 2 = f32 out + residual add
// ---------------------------------------------------------------------------
template <int OUT_MODE>
__global__ __launch_bounds__(256) void gemm_nt_kernel(const bf16_t* __restrict__ A,
                                                      const bf16_t* __restrict__ Bw,
                                                      void* __restrict__ Cout,
                                                      const float* __restrict__ resid,
                                                      int Mdim, int Ndim, int K) {
  constexpr int BM = 128, BN = 128, BK = 32;
  __shared__ bf16_t As[BM * BK];
  __shared__ bf16_t Bs[BN * BK];

  int tid = threadIdx.x;
  int lane = tid & 63;
  int wid = tid >> 6;
  int wm = wid >> 1, wn = wid & 1;
  int bm = blockIdx.x * BM;
  int bn = blockIdx.y * BN;
  int l15 = lane & 15;
  int l4 = lane >> 4;

  f32x4 acc[4][4];
#pragma unroll
  for (int i = 0; i < 4; i++)
#pragma unroll
    for (int j = 0; j < 4; j++) acc[i][j] = (f32x4){0.f, 0.f, 0.f, 0.f};

  const bf16_t* Ag = A + (size_t)bm * K;
  const bf16_t* Bg = Bw + (size_t)bn * K;
  int srow_lane = lane >> 2;
  int scol = (lane & 3) * 8;

  for (int k0 = 0; k0 < K; k0 += BK) {
#pragma unroll
    for (int i = 0; i < 2; i++) {
      int rbase = wid * 32 + i * 16;
      int r = rbase + srow_lane;
      __builtin_amdgcn_global_load_lds(
          (const __attribute__((address_space(1))) void*)(Ag + (size_t)r * K + k0 + scol),
          (__attribute__((address_space(3))) void*)(As + rbase * BK), 16, 0, 0);
      __builtin_amdgcn_global_load_lds(
          (const __attribute__((address_space(1))) void*)(Bg + (size_t)r * K + k0 + scol),
          (__attribute__((address_space(3))) void*)(Bs + rbase * BK), 16, 0, 0);
    }
    __syncthreads();

    const bf16x8* Asv = reinterpret_cast<const bf16x8*>(As);
    const bf16x8* Bsv = reinterpret_cast<const bf16x8*>(Bs);
    bf16x8 af[4], bfr[4];
#pragma unroll
    for (int mf = 0; mf < 4; mf++)
      af[mf] = Asv[(wm * 64 + mf * 16 + l15) * 4 + l4];
#pragma unroll
    for (int nf = 0; nf < 4; nf++)
      bfr[nf] = Bsv[(wn * 64 + nf * 16 + l15) * 4 + l4];
#pragma unroll
    for (int mf = 0; mf < 4; mf++)
#pragma unroll
      for (int nf = 0; nf < 4; nf++)
        acc[mf][nf] = __builtin_amdgcn_mfma_f32_16x16x32_bf16(af[mf], bfr[nf], acc[mf][nf], 0, 0, 0);
    __syncthreads();
  }

#pragma unroll
  for (int mf = 0; mf < 4; mf++)
#pragma unroll
    for (int nf = 0; nf < 4; nf++)
#pragma unroll
      for (int i = 0; i < 4; i++) {
        int row = bm + wm * 64 + mf * 16 + l4 * 4 + i;
        int col = bn + wn * 64 + nf * 16 + l15;
        size_t idx = (size_t)row * Ndim + col;
        float val = acc[mf][nf][i];
        if (OUT_MODE == 0) {
          ((float*)Cout)[idx] = val;
        } else {
          ((float*)Cout)[idx] = val + resid[idx];
        }
      }
}

// ---------------------------------------------------------------------------
// Big NT GEMM (logits): 256x256 tile, BK=64, 512 thr (8 waves 2Mx4N).
// 8-phase-per-iteration deep pipeline (4 phases per K-tile, 2 K-tiles' worth
// of state in flight), subtile-swizzled LDS (16x32 subtiles, XOR col-bit-4
// with row-bit-3), counted vmcnt(4) twice per K-tile (never 0 mid-loop),
// setprio around MFMA bursts. K hardcoded 1024. bf16 out.
//
// LDS element layout per K-tile buffer (A or B, 16384 elems):
//   elem(r,c) = ((r>>4)*2 + (c>>5))*512 + (r&15)*32 + ((c&31) ^ ((r&8)?16:0))
// Staged via linear global_load_lds with inverse-swizzled global source.
// ---------------------------------------------------------------------------
__global__ __launch_bounds__(512, 2) void gemm256_nt_kernel(const bf16_t* __restrict__ A,
                                                            const bf16_t* __restrict__ Bw,
                                                            bf16_t* __restrict__ C) {
  constexpr int K = 1024;
  constexpr int G = K / 64;        // 16 K-tiles
  __shared__ bf16_t As[2 * 16384];   // 64 KB
  __shared__ bf16_t Bs[2 * 16384];   // 64 KB

  const int tid = threadIdx.x;
  const int lane = tid & 63;
  const int w = tid >> 6;          // 0..7
  const int wm = w >> 2;           // 0..1
  const int wn = w & 3;            // 0..3
  const int l15 = lane & 15;
  const int l4 = lane >> 4;

  const int bm = blockIdx.x * 256;
  const int bn = blockIdx.y * 256;

  const bf16_t* Ag = A + (size_t)bm * K;
  const bf16_t* Bg = Bw + (size_t)bn * K;

  // per-thread staging source coords (inverse swizzle)
  int growi[2], gcoli[2];
#pragma unroll
  for (int j = 0; j < 2; ++j) {
    int E = j * 4096 + tid * 8;
    int sub = E >> 9, e = E & 511;
    int rin = e >> 5, cs = e & 31;
    int cin = cs ^ ((rin & 8) ? 16 : 0);
    growi[j] = (sub >> 1) * 16 + rin;    // 0..127
    gcoli[j] = (sub & 1) * 32 + cin;     // 0..63
  }

  // per-thread fragment base (swizzled) within a subtile
  const int fbase = l15 * 32 + ((l4 * 8) ^ ((l15 & 8) ? 16 : 0));

  f32x4 acc[8][4];
#pragma unroll
  for (int i = 0; i < 8; i++)
#pragma unroll
    for (int j = 0; j < 4; j++) acc[i][j] = (f32x4){0.f, 0.f, 0.f, 0.f};

  bf16x8 ALo[8], AHi[8], B0r[4], B1r[4];

  auto stageHalf = [&](const bf16_t* Gp, bf16_t* Lp, int bufp, int half, int t2) {
#pragma unroll
    for (int j = 0; j < 2; ++j) {
      const bf16_t* src = Gp + (size_t)(half * 128 + growi[j]) * K + t2 * 64 + gcoli[j];
      __builtin_amdgcn_global_load_lds(
          (const __attribute__((address_space(1))) void*)src,
          (__attribute__((address_space(3))) void*)(Lp + bufp * 16384 + half * 8192 + j * 4096 + w * 512),
          16, 0, 0);
    }
  };

  auto rdA = [&](bf16x8* dst, int bufp, int rgrpBase) {
    const bf16_t* base = As + bufp * 16384;
#pragma unroll
    for (int mf = 0; mf < 4; ++mf)
#pragma unroll
      for (int kk = 0; kk < 2; ++kk)
        dst[mf * 2 + kk] = *reinterpret_cast<const bf16x8*>(base + ((rgrpBase + mf) * 2 + kk) * 512 + fbase);
  };
  auto rdB = [&](bf16x8* dst, int bufp, int nfBase) {
    const bf16_t* base = Bs + bufp * 16384;
#pragma unroll
    for (int nf = 0; nf < 2; ++nf)
#pragma unroll
      for (int kk = 0; kk < 2; ++kk)
        dst[nf * 2 + kk] = *reinterpret_cast<const bf16x8*>(base + ((wn * 4 + nfBase + nf) * 2 + kk) * 512 + fbase);
  };
  auto MM = [&](const bf16x8* Af, const bf16x8* Bf, int mfB, int nfB) {
    __builtin_amdgcn_s_setprio(1);
#pragma unroll
    for (int mf = 0; mf < 4; ++mf)
#pragma unroll
      for (int nf = 0; nf < 2; ++nf)
#pragma unroll
        for (int kk = 0; kk < 2; ++kk)
          acc[mfB + mf][nfB + nf] = __builtin_amdgcn_mfma_f32_16x16x32_bf16(
              Af[mf * 2 + kk], Bf[nf * 2 + kk], acc[mfB + mf][nfB + nf], 0, 0, 0);
    __builtin_amdgcn_s_setprio(0);
  };

  // -------- prologue: stage B(0)->Bbuf0, A(0)->Abuf0, A(1)->Abuf1 --------
  stageHalf(Bg, Bs, 0, 0, 0);
  stageHalf(Bg, Bs, 0, 1, 0);
  stageHalf(Ag, As, 0, 0, 0);
  stageHalf(Ag, As, 0, 1, 0);
  stageHalf(Ag, As, 1, 0, 1);
  stageHalf(Ag, As, 1, 1, 1);
  asm volatile("s_waitcnt vmcnt(0)" ::: "memory");
  PBAR();
  rdA(ALo, 0, wm * 8);   // warmup: A-lo of tile 0

#pragma unroll 1
  for (int t = 0; t < G; ++t) {
    const int buf = t & 1;
    const int nbuf = buf ^ 1;

    // ---- P1: MFMA (ALo x B0) ----
    rdB(B0r, buf, 0);
    if (t + 1 < G) stageHalf(Bg, Bs, nbuf, 0, t + 1);
    PBAR();
    MM(ALo, B0r, 0, 0);
    PBAR();

    // ---- P2: MFMA (ALo x B1) ----
    rdB(B1r, buf, 2);
    rdA(AHi, buf, wm * 8 + 4);
    if (t + 1 < G) stageHalf(Bg, Bs, nbuf, 1, t + 1);
    PBAR();
    MM(ALo, B1r, 0, 2);
    // complete A(t+1) staging (leaves B(t+1)'s 4 gloads in flight)
    if (t + 1 < G) {
      if (t + 2 < G) asm volatile("s_waitcnt vmcnt(4)" ::: "memory");
      else           asm volatile("s_waitcnt vmcnt(4)" ::: "memory");
    }
    PBAR();

    // ---- P3: MFMA (AHi x B0) ----
    if (t + 1 < G) rdA(ALo, nbuf, wm * 8);      // A-lo of next tile
    if (t + 2 < G) stageHalf(Ag, As, buf, 0, t + 2);
    PBAR();
    MM(AHi, B0r, 4, 0);
    PBAR();

    // ---- P4: MFMA (AHi x B1) ----
    if (t + 2 < G) stageHalf(Ag, As, buf, 1, t + 2);
    PBAR();
    MM(AHi, B1r, 4, 2);
    // complete B(t+1) staging (leaves A(t+2)'s 4 gloads in flight)
    if (t + 2 < G)      asm volatile("s_waitcnt vmcnt(4)" ::: "memory");
    else if (t + 1 < G) asm volatile("s_waitcnt vmcnt(0)" ::: "memory");
    PBAR();
  }

  // -------- epilogue: C/D layout col = lane&15, row = 4*(lane>>4)+i --------
#pragma unroll
  for (int mf = 0; mf < 8; ++mf)
#pragma unroll
    for (int nf = 0; nf < 4; ++nf)
#pragma unroll
      for (int i = 0; i < 4; ++i) {
        int row = bm + wm * 128 + mf * 16 + l4 * 4 + i;
        int col = bn + wn * 64 + nf * 16 + l15;
        C[(size_t)row * NA + col] = (bf16_t)acc[mf][nf][i];
      }
}

// ---------------------------------------------------------------------------
// In-lane softmax over 17 logits
// ---------------------------------------------------------------------------
__device__ __forceinline__ void softmax17(const bf16_t* __restrict__ lp, float vval,
                                          f32x4& a0, f32x4& a1, f32x4& a2, f32x4& a3,
                                          float& u) {
  float e[17];
  float mx = -1e30f;
#pragma unroll
  for (int j = 0; j < 17; ++j) {
    e[j] = (float)lp[j];
    mx = fmaxf(mx, e[j]);
  }
  float s = 0.f;
#pragma unroll
  for (int j = 0; j < 17; ++j) {
    e[j] = __expf(e[j] - mx);
    s += e[j];
  }
  float inv = 1.0f / s;
  a0 = (f32x4){e[1] * inv, e[2] * inv, e[3] * inv, e[4] * inv};
  a1 = (f32x4){e[5] * inv, e[6] * inv, e[7] * inv, e[8] * inv};
  a2 = (f32x4){e[9] * inv, e[10] * inv, e[11] * inv, e[12] * inv};
  a3 = (f32x4){e[13] * inv, e[14] * inv, e[15] * inv, e[16] * inv};
  u = e[0] * inv * vval;
}

// ---------------------------------------------------------------------------
// scanA: per (chain, chunk) chunk summary (P, q)
// ---------------------------------------------------------------------------
__global__ __launch_bounds__(256) void scanA_kernel(const bf16_t* __restrict__ lg,
                                                    const float* __restrict__ v,
                                                    float* __restrict__ sum) {
  int bc = blockIdx.x;
  int b = bc >> 6;
  int c = bc & 63;
  int g = threadIdx.x >> 4;
  int i = threadIdx.x & 15;
  int h = blockIdx.y * 16 + g;
  int chain = b * 64 + h;

  __shared__ float Arows[16][16][16];
  __shared__ float Us[16][16];

  f32x4 R0 = (f32x4){i == 0 ? 1.f : 0.f, i == 1 ? 1.f : 0.f, i == 2 ? 1.f : 0.f, i == 3 ? 1.f : 0.f};
  f32x4 R1 = (f32x4){i == 4 ? 1.f : 0.f, i == 5 ? 1.f : 0.f, i == 6 ? 1.f : 0.f, i == 7 ? 1.f : 0.f};
  f32x4 R2 = (f32x4){i == 8 ? 1.f : 0.f, i == 9 ? 1.f : 0.f, i == 10 ? 1.f : 0.f, i == 11 ? 1.f : 0.f};
  f32x4 R3 = (f32x4){i == 12 ? 1.f : 0.f, i == 13 ? 1.f : 0.f, i == 14 ? 1.f : 0.f, i == 15 ? 1.f : 0.f};
  float q = 0.f;

#pragma unroll 1
  for (int tau = CL - 1; tau >= 0; --tau) {
    int r = b * T_DIM + c * CL + tau;
    const bf16_t* lp = lg + (size_t)r * NA + h * 272 + i * 17;
    float vval = v[(size_t)r * D_DIM + h * 16 + i];
    f32x4 a0, a1, a2, a3;
    float uu;
    softmax17(lp, vval, a0, a1, a2, a3, uu);

    *reinterpret_cast<f32x4*>(&Arows[g][i][0]) = a0;
    *reinterpret_cast<f32x4*>(&Arows[g][i][4]) = a1;
    *reinterpret_cast<f32x4*>(&Arows[g][i][8]) = a2;
    *reinterpret_cast<f32x4*>(&Arows[g][i][12]) = a3;
    Us[g][i] = uu;
    asm volatile("s_waitcnt lgkmcnt(0)" ::: "memory");
    __builtin_amdgcn_sched_barrier(0);

    f32x4 u0 = *reinterpret_cast<const f32x4*>(&Us[g][0]);
    f32x4 u1 = *reinterpret_cast<const f32x4*>(&Us[g][4]);
    f32x4 u2 = *reinterpret_cast<const f32x4*>(&Us[g][8]);
    f32x4 u3 = *reinterpret_cast<const f32x4*>(&Us[g][12]);
    float qa = fmaf(R0[0], u0[0], fmaf(R0[1], u0[1], fmaf(R0[2], u0[2], R0[3] * u0[3])));
    float qb = fmaf(R1[0], u1[0], fmaf(R1[1], u1[1], fmaf(R1[2], u1[2], R1[3] * u1[3])));
    float qc = fmaf(R2[0], u2[0], fmaf(R2[1], u2[1], fmaf(R2[2], u2[2], R2[3] * u2[3])));
    float qd = fmaf(R3[0], u3[0], fmaf(R3[1], u3[1], fmaf(R3[2], u3[2], R3[3] * u3[3])));
    q += (qa + qb) + (qc + qd);

    f32x4 n0 = (f32x4){0.f, 0.f, 0.f, 0.f}, n1 = n0, n2 = n0, n3 = n0;
#pragma unroll
    for (int k = 0; k < 16; ++k) {
      float rk = (k < 4) ? R0[k & 3] : (k < 8) ? R1[k & 3] : (k < 12) ? R2[k & 3] : R3[k & 3];
      f32x4 b0 = *reinterpret_cast<const f32x4*>(&Arows[g][k][0]);
      f32x4 b1 = *reinterpret_cast<const f32x4*>(&Arows[g][k][4]);
      f32x4 b2 = *reinterpret_cast<const f32x4*>(&Arows[g][k][8]);
      f32x4 b3 = *reinterpret_cast<const f32x4*>(&Arows[g][k][12]);
#pragma unroll
      for (int e2 = 0; e2 < 4; ++e2) {
        n0[e2] = fmaf(rk, b0[e2], n0[e2]);
        n1[e2] = fmaf(rk, b1[e2], n1[e2]);
        n2[e2] = fmaf(rk, b2[e2], n2[e2]);
        n3[e2] = fmaf(rk, b3[e2], n3[e2]);
      }
    }
    R0 = n0; R1 = n1; R2 = n2; R3 = n3;
  }

  float* sp = sum + (size_t)(chain * NC + c) * 272;
  *reinterpret_cast<f32x4*>(&sp[i * 16 + 0]) = R0;
  *reinterpret_cast<f32x4*>(&sp[i * 16 + 4]) = R1;
  *reinterpret_cast<f32x4*>(&sp[i * 16 + 8]) = R2;
  *reinterpret_cast<f32x4*>(&sp[i * 16 + 12]) = R3;
  sp[256 + i] = q;
}

// ---------------------------------------------------------------------------
// scanB: serial scan over 64 chunk summaries per chain
// ---------------------------------------------------------------------------
__global__ __launch_bounds__(64) void scanB_kernel(const float* __restrict__ sum,
                                                   float* __restrict__ sinit) {
  int chain = blockIdx.x;
  int lane = threadIdx.x;
  int i = lane & 15;

  __shared__ float seg[2][2176];

  const float* gbase = sum + (size_t)chain * NC * 272;

  auto load_seg = [&](int s, int buf) {
#pragma unroll
    for (int r = 0; r < 9; ++r) {
      int idx = r * 256 + lane * 4;
      if (idx < 2176) {
        __builtin_amdgcn_global_load_lds(
            (const __attribute__((address_space(1))) void*)(gbase + (size_t)s * 2176 + idx),
            (__attribute__((address_space(3))) void*)(&seg[buf][r * 256]), 16, 0, 0);
      }
    }
  };

  load_seg(0, 0);
  asm volatile("s_waitcnt vmcnt(0)" ::: "memory");
  __builtin_amdgcn_sched_barrier(0);

  f32x4 S0 = (f32x4){0.f, 0.f, 0.f, 0.f}, S1 = S0, S2 = S0, S3 = S0;
  float own = 0.f;

  for (int sg = 0; sg < 8; ++sg) {
    int buf = sg & 1;
    if (sg + 1 < 8) load_seg(sg + 1, buf ^ 1);
#pragma unroll 1
    for (int cc = 0; cc < 8; ++cc) {
      int c = sg * 8 + cc;
      const float* Pb = &seg[buf][cc * 272];
      if (lane < 16) sinit[(size_t)(chain * NC + c) * 16 + i] = own;

      f32x4 p0 = *reinterpret_cast<const f32x4*>(&Pb[i * 16 + 0]);
      f32x4 p1 = *reinterpret_cast<const f32x4*>(&Pb[i * 16 + 4]);
      f32x4 p2 = *reinterpret_cast<const f32x4*>(&Pb[i * 16 + 8]);
      f32x4 p3 = *reinterpret_cast<const f32x4*>(&Pb[i * 16 + 12]);
      float qq = Pb[256 + i];

      float pa = fmaf(p0[0], S0[0], fmaf(p0[1], S0[1], fmaf(p0[2], S0[2], p0[3] * S0[3])));
      float pb = fmaf(p1[0], S1[0], fmaf(p1[1], S1[1], fmaf(p1[2], S1[2], p1[3] * S1[3])));
      float pc = fmaf(p2[0], S2[0], fmaf(p2[1], S2[1], fmaf(p2[2], S2[2], p2[3] * S2[3])));
      float pd = fmaf(p3[0], S3[0], fmaf(p3[1], S3[1], fmaf(p3[2], S3[2], p3[3] * S3[3])));
      float p = (pa + pb) + (pc + pd) + qq;
      own = p;

#pragma unroll
      for (int j = 0; j < 4; ++j) {
        S0[j] = __shfl(p, j, 64);
        S1[j] = __shfl(p, 4 + j, 64);
        S2[j] = __shfl(p, 8 + j, 64);
        S3[j] = __shfl(p, 12 + j, 64);
      }
    }
    if (sg + 1 < 8) {
      asm volatile("s_waitcnt vmcnt(0)" ::: "memory");
      __builtin_amdgcn_sched_barrier(0);
    }
  }
}

// ---------------------------------------------------------------------------
// scanC: re-run each chunk from its s_init, writing y
// ---------------------------------------------------------------------------
__global__ __launch_bounds__(256) void scanC_kernel(const bf16_t* __restrict__ lg,
                                                    const float* __restrict__ v,
                                                    const float* __restrict__ sinit,
                                                    bf16_t* __restrict__ y) {
  int bc = blockIdx.x;
  int b = bc >> 6;
  int c = bc & 63;
  int g = threadIdx.x >> 4;
  int i = threadIdx.x & 15;
  int h = blockIdx.y * 16 + g;
  int chain = b * 64 + h;

  __shared__ float Sb[16][16];

  const float* ip = sinit + (size_t)(chain * NC + c) * 16;
  f32x4 S0 = *reinterpret_cast<const f32x4*>(&ip[0]);
  f32x4 S1 = *reinterpret_cast<const f32x4*>(&ip[4]);
  f32x4 S2 = *reinterpret_cast<const f32x4*>(&ip[8]);
  f32x4 S3 = *reinterpret_cast<const f32x4*>(&ip[12]);

#pragma unroll 1
  for (int t = 0; t < CL; ++t) {
    int r = b * T_DIM + c * CL + t;
    const bf16_t* lp = lg + (size_t)r * NA + h * 272 + i * 17;
    float vval = v[(size_t)r * D_DIM + h * 16 + i];
    f32x4 a0, a1, a2, a3;
    float uu;
    softmax17(lp, vval, a0, a1, a2, a3, uu);

    float pa = fmaf(a0[0], S0[0], fmaf(a0[1], S0[1], fmaf(a0[2], S0[2], a0[3] * S0[3])));
    float pb = fmaf(a1[0], S1[0], fmaf(a1[1], S1[1], fmaf(a1[2], S1[2], a1[3] * S1[3])));
    float pc = fmaf(a2[0], S2[0], fmaf(a2[1], S2[1], fmaf(a2[2], S2[2], a2[3] * S2[3])));
    float pd = fmaf(a3[0], S3[0], fmaf(a3[1], S3[1], fmaf(a3[2], S3[2], a3[3] * S3[3])));
    float p = (pa + pb) + (pc + pd) + uu;

    y[(size_t)r * D_DIM + h * 16 + i] = (bf16_t)p;

    Sb[g][i] = p;
    asm volatile("s_waitcnt lgkmcnt(0)" ::: "memory");
    __builtin_amdgcn_sched_barrier(0);
    S0 = *reinterpret_cast<const f32x4*>(&Sb[g][0]);
    S1 = *reinterpret_cast<const f32x4*>(&Sb[g][4]);
    S2 = *reinterpret_cast<const f32x4*>(&Sb[g][8]);
    S3 = *reinterpret_cast<const f32x4*>(&Sb[g][12]);
  }
}

// ---------------------------------------------------------------------------
extern "C" void kernel_launch(void* const* d_in, const int* in_sizes, int n_in,
                              void* d_out, int out_size, void* d_ws, size_t ws_size,
                              hipStream_t stream) {
  const float* x      = (const float*)d_in[0];
  const float* norm_w = (const float*)d_in[1];
  const float* W_v    = (const float*)d_in[2];
  const float* W_a    = (const float*)d_in[3];
  const float* W_out  = (const float*)d_in[4];

  char* ws = (char*)d_ws;
  size_t off = 0;
  auto alloc = [&](size_t bytes) {
    void* p = ws + off;
    off += (bytes + 255) & ~(size_t)255;
    return p;
  };
  bf16_t* wv_b = (bf16_t*)alloc((size_t)D_DIM * D_DIM * 2);        // 2 MB
  bf16_t* wa_b = (bf16_t*)alloc((size_t)NA * D_DIM * 2);           // 35.7 MB
  bf16_t* wo_b = (bf16_t*)alloc((size_t)D_DIM * D_DIM * 2);        // 2 MB
  bf16_t* h_b  = (bf16_t*)alloc((size_t)NT * D_DIM * 2);           // 8 MB
  float*  v_f  = (float*)alloc((size_t)NT * D_DIM * 4);            // 16 MB
  bf16_t* lg_b = (bf16_t*)alloc((size_t)NT * NA * 2);              // 142.6 MB
  bf16_t* y_b  = (bf16_t*)alloc((size_t)NT * D_DIM * 2);           // 8 MB
  float*  sum_f   = (float*)alloc((size_t)256 * NC * 272 * 4);     // 17.8 MB
  float*  sinit_f = (float*)alloc((size_t)256 * NC * 16 * 4);      // 1.05 MB

  cvt_kernel<<<1024, 256, 0, stream>>>(W_v, wv_b, D_DIM * D_DIM / 4);
  cvt_kernel<<<1024, 256, 0, stream>>>(W_a, wa_b, NA * D_DIM / 4);
  cvt_kernel<<<1024, 256, 0, stream>>>(W_out, wo_b, D_DIM * D_DIM / 4);

  rmsnorm_kernel<<<NT, 256, 0, stream>>>(x, norm_w, h_b);

  gemm_nt_kernel<0><<<dim3(NT / 128, D_DIM / 128), 256, 0, stream>>>(
      h_b, wv_b, (void*)v_f, nullptr, NT, D_DIM, D_DIM);

  gemm256_nt_kernel<<<dim3(NT / 256, NA / 256), 512, 0, stream>>>(h_b, wa_b, lg_b);

  scanA_kernel<<<dim3(256, 4), 256, 0, stream>>>(lg_b, v_f, sum_f);
  scanB_kernel<<<256, 64, 0, stream>>>(sum_f, sinit_f);
  scanC_kernel<<<dim3(256, 4), 256, 0, stream>>>(lg_b, v_f, sinit_f, y_b);

  gemm_nt_kernel<2><<<dim3(NT / 128, D_DIM / 128), 256, 0, stream>>>(
      y_b, wo_b, d_out, x, NT, D_DIM, D_DIM);
}

// Round 7
// 334.581 us; speedup vs baseline: 1.4608x; 1.0941x over previous
//
#include <hip/hip_runtime.h>
#include <hip/hip_bf16.h>
#include <math.h>

// Problem constants
#define B_DIM 4
#define T_DIM 1024
#define D_DIM 1024
#define M_DIM 16
#define H_DIM 64
#define NT    4096            // B*T
#define NA    17408           // H*M*(M+1)
#define NCAT  18432           // NA + D (v-GEMM fused)
#define EPSV  1e-5f
#define CL    16              // scan chunk length
#define NC    64              // chunks per chain (T/CL)

typedef __bf16 bf16_t;
typedef __bf16 bf16x4 __attribute__((ext_vector_type(4)));
typedef __bf16 bf16x8 __attribute__((ext_vector_type(8)));
typedef float  f32x4  __attribute__((ext_vector_type(4)));

#define PBAR() do { asm volatile("" ::: "memory"); __builtin_amdgcn_s_barrier(); asm volatile("" ::: "memory"); } while (0)

// ---------------------------------------------------------------------------
// One cvt kernel for all three weight matrices.
// wcat rows [0,17408) = W_a ; rows [17408,18432) = W_v ; wo separate.
// ---------------------------------------------------------------------------
__global__ __launch_bounds__(256) void cvt_all_kernel(const float* __restrict__ Wa,
                                                      const float* __restrict__ Wv,
                                                      const float* __restrict__ Wo,
                                                      bf16_t* __restrict__ wcat,
                                                      bf16_t* __restrict__ wo) {
  constexpr int NA4 = NA * D_DIM / 4;
  constexpr int NV4 = D_DIM * D_DIM / 4;
  constexpr int total = NA4 + 2 * NV4;
  int idx = blockIdx.x * blockDim.x + threadIdx.x;
  int stride = gridDim.x * blockDim.x;
  for (; idx < total; idx += stride) {
    const float* src; bf16_t* dst; int j;
    if (idx < NA4)            { src = Wa; dst = wcat; j = idx; }
    else if (idx < NA4 + NV4) { src = Wv; dst = wcat + (size_t)NA * D_DIM; j = idx - NA4; }
    else                      { src = Wo; dst = wo; j = idx - NA4 - NV4; }
    float4 v = reinterpret_cast<const float4*>(src)[j];
    bf16x4 o;
    o[0] = (bf16_t)v.x; o[1] = (bf16_t)v.y; o[2] = (bf16_t)v.z; o[3] = (bf16_t)v.w;
    reinterpret_cast<bf16x4*>(dst)[j] = o;
  }
}

// ---------------------------------------------------------------------------
// RMSNorm
// ---------------------------------------------------------------------------
__global__ __launch_bounds__(256) void rmsnorm_kernel(const float* __restrict__ x,
                                                      const float* __restrict__ w,
                                                      bf16_t* __restrict__ h) {
  int row = blockIdx.x;
  int tid = threadIdx.x;
  const float4* xr = reinterpret_cast<const float4*>(x + (size_t)row * D_DIM);
  float4 xv = xr[tid];
  float ss = xv.x * xv.x + xv.y * xv.y + xv.z * xv.z + xv.w * xv.w;
#pragma unroll
  for (int m = 1; m < 64; m <<= 1) ss += __shfl_xor(ss, m, 64);
  __shared__ float red[4];
  int lane = tid & 63, wid = tid >> 6;
  if (lane == 0) red[wid] = ss;
  __syncthreads();
  float tot = red[0] + red[1] + red[2] + red[3];
  float scale = rsqrtf(tot * (1.0f / D_DIM) + EPSV);
  float4 wv = reinterpret_cast<const float4*>(w)[tid];
  bf16x4 o;
  o[0] = (bf16_t)(xv.x * scale * wv.x);
  o[1] = (bf16_t)(xv.y * scale * wv.y);
  o[2] = (bf16_t)(xv.z * scale * wv.z);
  o[3] = (bf16_t)(xv.w * scale * wv.w);
  reinterpret_cast<bf16x4*>(h)[(size_t)row * 256 + tid] = o;
}

// ---------------------------------------------------------------------------
// Small NT GEMM: 128x128 tile, BK=32 — final projection with residual add.
// ---------------------------------------------------------------------------
__global__ __launch_bounds__(256) void gemm_out_kernel(const bf16_t* __restrict__ A,
                                                       const bf16_t* __restrict__ Bw,
                                                       float* __restrict__ Cout,
                                                       const float* __restrict__ resid,
                                                       int Ndim, int K) {
  constexpr int BM = 128, BN = 128, BK = 32;
  __shared__ bf16_t As[BM * BK];
  __shared__ bf16_t Bs[BN * BK];

  int tid = threadIdx.x;
  int lane = tid & 63;
  int wid = tid >> 6;
  int wm = wid >> 1, wn = wid & 1;
  int bm = blockIdx.x * BM;
  int bn = blockIdx.y * BN;
  int l15 = lane & 15;
  int l4 = lane >> 4;

  f32x4 acc[4][4];
#pragma unroll
  for (int i = 0; i < 4; i++)
#pragma unroll
    for (int j = 0; j < 4; j++) acc[i][j] = (f32x4){0.f, 0.f, 0.f, 0.f};

  const bf16_t* Ag = A + (size_t)bm * K;
  const bf16_t* Bg = Bw + (size_t)bn * K;
  int srow_lane = lane >> 2;
  int scol = (lane & 3) * 8;

  for (int k0 = 0; k0 < K; k0 += BK) {
#pragma unroll
    for (int i = 0; i < 2; i++) {
      int rbase = wid * 32 + i * 16;
      int r = rbase + srow_lane;
      __builtin_amdgcn_global_load_lds(
          (const __attribute__((address_space(1))) void*)(Ag + (size_t)r * K + k0 + scol),
          (__attribute__((address_space(3))) void*)(As + rbase * BK), 16, 0, 0);
      __builtin_amdgcn_global_load_lds(
          (const __attribute__((address_space(1))) void*)(Bg + (size_t)r * K + k0 + scol),
          (__attribute__((address_space(3))) void*)(Bs + rbase * BK), 16, 0, 0);
    }
    __syncthreads();

    const bf16x8* Asv = reinterpret_cast<const bf16x8*>(As);
    const bf16x8* Bsv = reinterpret_cast<const bf16x8*>(Bs);
    bf16x8 af[4], bfr[4];
#pragma unroll
    for (int mf = 0; mf < 4; mf++)
      af[mf] = Asv[(wm * 64 + mf * 16 + l15) * 4 + l4];
#pragma unroll
    for (int nf = 0; nf < 4; nf++)
      bfr[nf] = Bsv[(wn * 64 + nf * 16 + l15) * 4 + l4];
#pragma unroll
    for (int mf = 0; mf < 4; mf++)
#pragma unroll
      for (int nf = 0; nf < 4; nf++)
        acc[mf][nf] = __builtin_amdgcn_mfma_f32_16x16x32_bf16(af[mf], bfr[nf], acc[mf][nf], 0, 0, 0);
    __syncthreads();
  }

#pragma unroll
  for (int mf = 0; mf < 4; mf++)
#pragma unroll
    for (int nf = 0; nf < 4; nf++)
#pragma unroll
      for (int i = 0; i < 4; i++) {
        int row = bm + wm * 64 + mf * 16 + l4 * 4 + i;
        int col = bn + wn * 64 + nf * 16 + l15;
        size_t idx = (size_t)row * Ndim + col;
        Cout[idx] = acc[mf][nf][i] + resid[idx];
      }
}

// ---------------------------------------------------------------------------
// Big NT GEMM (logits + v fused): 256x256 tile, BK=64, 512 thr (8 waves 2Mx4N),
// 4-phase/K-tile deep pipeline, subtile-swizzled LDS (16x32, XOR col-bit-4 with
// row-bit-3), counted vmcnt(4) twice per K-tile, setprio around MFMA bursts.
// N = 18432: blockIdx.y < 68 -> logits (bf16, stride NA);
//            blockIdx.y >= 68 -> v (f32, stride D).
// ---------------------------------------------------------------------------
__global__ __launch_bounds__(512, 2) void gemm256_nt_kernel(const bf16_t* __restrict__ A,
                                                            const bf16_t* __restrict__ Bw,
                                                            bf16_t* __restrict__ Clg,
                                                            float* __restrict__ Cv) {
  constexpr int K = 1024;
  constexpr int G = K / 64;        // 16 K-tiles
  __shared__ bf16_t As[2 * 16384];   // 64 KB
  __shared__ bf16_t Bs[2 * 16384];   // 64 KB

  const int tid = threadIdx.x;
  const int lane = tid & 63;
  const int w = tid >> 6;          // 0..7
  const int wm = w >> 2;           // 0..1
  const int wn = w & 3;            // 0..3
  const int l15 = lane & 15;
  const int l4 = lane >> 4;

  const int bm = blockIdx.x * 256;
  const int bn = blockIdx.y * 256;

  const bf16_t* Ag = A + (size_t)bm * K;
  const bf16_t* Bg = Bw + (size_t)bn * K;

  // per-thread staging source coords (inverse swizzle)
  int growi[2], gcoli[2];
#pragma unroll
  for (int j = 0; j < 2; ++j) {
    int E = j * 4096 + tid * 8;
    int sub = E >> 9, e = E & 511;
    int rin = e >> 5, cs = e & 31;
    int cin = cs ^ ((rin & 8) ? 16 : 0);
    growi[j] = (sub >> 1) * 16 + rin;    // 0..127
    gcoli[j] = (sub & 1) * 32 + cin;     // 0..63
  }

  // per-thread fragment base (swizzled) within a subtile
  const int fbase = l15 * 32 + ((l4 * 8) ^ ((l15 & 8) ? 16 : 0));

  f32x4 acc[8][4];
#pragma unroll
  for (int i = 0; i < 8; i++)
#pragma unroll
    for (int j = 0; j < 4; j++) acc[i][j] = (f32x4){0.f, 0.f, 0.f, 0.f};

  bf16x8 ALo[8], AHi[8], B0r[4], B1r[4];

  auto stageHalf = [&](const bf16_t* Gp, bf16_t* Lp, int bufp, int half, int t2) {
#pragma unroll
    for (int j = 0; j < 2; ++j) {
      const bf16_t* src = Gp + (size_t)(half * 128 + growi[j]) * K + t2 * 64 + gcoli[j];
      __builtin_amdgcn_global_load_lds(
          (const __attribute__((address_space(1))) void*)src,
          (__attribute__((address_space(3))) void*)(Lp + bufp * 16384 + half * 8192 + j * 4096 + w * 512),
          16, 0, 0);
    }
  };

  auto rdA4 = [&](bf16x8* dst, int bufp, int rgrpBase) {   // 4 fragments (8 reads)
    const bf16_t* base = As + bufp * 16384;
#pragma unroll
    for (int mf = 0; mf < 4; ++mf)
#pragma unroll
      for (int kk = 0; kk < 2; ++kk)
        dst[mf * 2 + kk] = *reinterpret_cast<const bf16x8*>(base + ((rgrpBase + mf) * 2 + kk) * 512 + fbase);
  };
  auto rdA2 = [&](bf16x8* dst, int bufp, int rgrpBase) {   // 2 fragments (4 reads)
    const bf16_t* base = As + bufp * 16384;
#pragma unroll
    for (int mf = 0; mf < 2; ++mf)
#pragma unroll
      for (int kk = 0; kk < 2; ++kk)
        dst[mf * 2 + kk] = *reinterpret_cast<const bf16x8*>(base + ((rgrpBase + mf) * 2 + kk) * 512 + fbase);
  };
  auto rdB = [&](bf16x8* dst, int bufp, int nfBase) {
    const bf16_t* base = Bs + bufp * 16384;
#pragma unroll
    for (int nf = 0; nf < 2; ++nf)
#pragma unroll
      for (int kk = 0; kk < 2; ++kk)
        dst[nf * 2 + kk] = *reinterpret_cast<const bf16x8*>(base + ((wn * 4 + nfBase + nf) * 2 + kk) * 512 + fbase);
  };
  auto MM = [&](const bf16x8* Af, const bf16x8* Bf, int mfB, int nfB) {
    __builtin_amdgcn_s_setprio(1);
#pragma unroll
    for (int mf = 0; mf < 4; ++mf)
#pragma unroll
      for (int nf = 0; nf < 2; ++nf)
#pragma unroll
        for (int kk = 0; kk < 2; ++kk)
          acc[mfB + mf][nfB + nf] = __builtin_amdgcn_mfma_f32_16x16x32_bf16(
              Af[mf * 2 + kk], Bf[nf * 2 + kk], acc[mfB + mf][nfB + nf], 0, 0, 0);
    __builtin_amdgcn_s_setprio(0);
  };

  // -------- prologue --------
  stageHalf(Bg, Bs, 0, 0, 0);
  stageHalf(Bg, Bs, 0, 1, 0);
  stageHalf(Ag, As, 0, 0, 0);
  stageHalf(Ag, As, 0, 1, 0);
  stageHalf(Ag, As, 1, 0, 1);
  stageHalf(Ag, As, 1, 1, 1);
  asm volatile("s_waitcnt vmcnt(0)" ::: "memory");
  PBAR();
  rdA4(ALo, 0, wm * 8);   // warmup: A-lo of tile 0

#pragma unroll 1
  for (int t = 0; t < G; ++t) {
    const int buf = t & 1;
    const int nbuf = buf ^ 1;

    // ---- P1: MFMA (ALo x B0) ----
    rdB(B0r, buf, 0);
    rdA2(AHi, buf, wm * 8 + 4);                 // first half of AHi
    if (t + 1 < G) stageHalf(Bg, Bs, nbuf, 0, t + 1);
    PBAR();
    MM(ALo, B0r, 0, 0);
    PBAR();

    // ---- P2: MFMA (ALo x B1) ----
    rdB(B1r, buf, 2);
    rdA2(AHi + 4, buf, wm * 8 + 6);             // second half of AHi
    if (t + 1 < G) stageHalf(Bg, Bs, nbuf, 1, t + 1);
    PBAR();
    MM(ALo, B1r, 0, 2);
    if (t + 1 < G) asm volatile("s_waitcnt vmcnt(4)" ::: "memory");
    PBAR();

    // ---- P3: MFMA (AHi x B0) ----
    if (t + 1 < G) rdA4(ALo, nbuf, wm * 8);     // A-lo of next tile
    if (t + 2 < G) stageHalf(Ag, As, buf, 0, t + 2);
    PBAR();
    MM(AHi, B0r, 4, 0);
    PBAR();

    // ---- P4: MFMA (AHi x B1) ----
    if (t + 2 < G) stageHalf(Ag, As, buf, 1, t + 2);
    PBAR();
    MM(AHi, B1r, 4, 2);
    if (t + 2 < G)      asm volatile("s_waitcnt vmcnt(4)" ::: "memory");
    else if (t + 1 < G) asm volatile("s_waitcnt vmcnt(0)" ::: "memory");
    PBAR();
  }

  // -------- epilogue --------
  if (blockIdx.y < 68) {
#pragma unroll
    for (int mf = 0; mf < 8; ++mf)
#pragma unroll
      for (int nf = 0; nf < 4; ++nf)
#pragma unroll
        for (int i = 0; i < 4; ++i) {
          int row = bm + wm * 128 + mf * 16 + l4 * 4 + i;
          int col = bn + wn * 64 + nf * 16 + l15;
          Clg[(size_t)row * NA + col] = (bf16_t)acc[mf][nf][i];
        }
  } else {
    int cb = bn - NA;
#pragma unroll
    for (int mf = 0; mf < 8; ++mf)
#pragma unroll
      for (int nf = 0; nf < 4; ++nf)
#pragma unroll
        for (int i = 0; i < 4; ++i) {
          int row = bm + wm * 128 + mf * 16 + l4 * 4 + i;
          int col = cb + wn * 64 + nf * 16 + l15;
          Cv[(size_t)row * D_DIM + col] = acc[mf][nf][i];
        }
  }
}

// ---------------------------------------------------------------------------
// In-lane softmax over 17 logits
// ---------------------------------------------------------------------------
__device__ __forceinline__ void softmax17(const bf16_t* __restrict__ lp, float vval,
                                          f32x4& a0, f32x4& a1, f32x4& a2, f32x4& a3,
                                          float& u) {
  float e[17];
  float mx = -1e30f;
#pragma unroll
  for (int j = 0; j < 17; ++j) {
    e[j] = (float)lp[j];
    mx = fmaxf(mx, e[j]);
  }
  float s = 0.f;
#pragma unroll
  for (int j = 0; j < 17; ++j) {
    e[j] = __expf(e[j] - mx);
    s += e[j];
  }
  float inv = 1.0f / s;
  a0 = (f32x4){e[1] * inv, e[2] * inv, e[3] * inv, e[4] * inv};
  a1 = (f32x4){e[5] * inv, e[6] * inv, e[7] * inv, e[8] * inv};
  a2 = (f32x4){e[9] * inv, e[10] * inv, e[11] * inv, e[12] * inv};
  a3 = (f32x4){e[13] * inv, e[14] * inv, e[15] * inv, e[16] * inv};
  u = e[0] * inv * vval;
}

// ---------------------------------------------------------------------------
// scanA: per (chain, chunk) chunk summary (P, q)
// ---------------------------------------------------------------------------
__global__ __launch_bounds__(256) void scanA_kernel(const bf16_t* __restrict__ lg,
                                                    const float* __restrict__ v,
                                                    float* __restrict__ sum) {
  int bc = blockIdx.x;
  int b = bc >> 6;
  int c = bc & 63;
  int g = threadIdx.x >> 4;
  int i = threadIdx.x & 15;
  int h = blockIdx.y * 16 + g;
  int chain = b * 64 + h;

  __shared__ float Arows[16][16][16];
  __shared__ float Us[16][16];

  f32x4 R0 = (f32x4){i == 0 ? 1.f : 0.f, i == 1 ? 1.f : 0.f, i == 2 ? 1.f : 0.f, i == 3 ? 1.f : 0.f};
  f32x4 R1 = (f32x4){i == 4 ? 1.f : 0.f, i == 5 ? 1.f : 0.f, i == 6 ? 1.f : 0.f, i == 7 ? 1.f : 0.f};
  f32x4 R2 = (f32x4){i == 8 ? 1.f : 0.f, i == 9 ? 1.f : 0.f, i == 10 ? 1.f : 0.f, i == 11 ? 1.f : 0.f};
  f32x4 R3 = (f32x4){i == 12 ? 1.f : 0.f, i == 13 ? 1.f : 0.f, i == 14 ? 1.f : 0.f, i == 15 ? 1.f : 0.f};
  float q = 0.f;

#pragma unroll 1
  for (int tau = CL - 1; tau >= 0; --tau) {
    int r = b * T_DIM + c * CL + tau;
    const bf16_t* lp = lg + (size_t)r * NA + h * 272 + i * 17;
    float vval = v[(size_t)r * D_DIM + h * 16 + i];
    f32x4 a0, a1, a2, a3;
    float uu;
    softmax17(lp, vval, a0, a1, a2, a3, uu);

    *reinterpret_cast<f32x4*>(&Arows[g][i][0]) = a0;
    *reinterpret_cast<f32x4*>(&Arows[g][i][4]) = a1;
    *reinterpret_cast<f32x4*>(&Arows[g][i][8]) = a2;
    *reinterpret_cast<f32x4*>(&Arows[g][i][12]) = a3;
    Us[g][i] = uu;
    asm volatile("s_waitcnt lgkmcnt(0)" ::: "memory");
    __builtin_amdgcn_sched_barrier(0);

    f32x4 u0 = *reinterpret_cast<const f32x4*>(&Us[g][0]);
    f32x4 u1 = *reinterpret_cast<const f32x4*>(&Us[g][4]);
    f32x4 u2 = *reinterpret_cast<const f32x4*>(&Us[g][8]);
    f32x4 u3 = *reinterpret_cast<const f32x4*>(&Us[g][12]);
    float qa = fmaf(R0[0], u0[0], fmaf(R0[1], u0[1], fmaf(R0[2], u0[2], R0[3] * u0[3])));
    float qb = fmaf(R1[0], u1[0], fmaf(R1[1], u1[1], fmaf(R1[2], u1[2], R1[3] * u1[3])));
    float qc = fmaf(R2[0], u2[0], fmaf(R2[1], u2[1], fmaf(R2[2], u2[2], R2[3] * u2[3])));
    float qd = fmaf(R3[0], u3[0], fmaf(R3[1], u3[1], fmaf(R3[2], u3[2], R3[3] * u3[3])));
    q += (qa + qb) + (qc + qd);

    f32x4 n0 = (f32x4){0.f, 0.f, 0.f, 0.f}, n1 = n0, n2 = n0, n3 = n0;
#pragma unroll
    for (int k = 0; k < 16; ++k) {
      float rk = (k < 4) ? R0[k & 3] : (k < 8) ? R1[k & 3] : (k < 12) ? R2[k & 3] : R3[k & 3];
      f32x4 b0 = *reinterpret_cast<const f32x4*>(&Arows[g][k][0]);
      f32x4 b1 = *reinterpret_cast<const f32x4*>(&Arows[g][k][4]);
      f32x4 b2 = *reinterpret_cast<const f32x4*>(&Arows[g][k][8]);
      f32x4 b3 = *reinterpret_cast<const f32x4*>(&Arows[g][k][12]);
#pragma unroll
      for (int e2 = 0; e2 < 4; ++e2) {
        n0[e2] = fmaf(rk, b0[e2], n0[e2]);
        n1[e2] = fmaf(rk, b1[e2], n1[e2]);
        n2[e2] = fmaf(rk, b2[e2], n2[e2]);
        n3[e2] = fmaf(rk, b3[e2], n3[e2]);
      }
    }
    R0 = n0; R1 = n1; R2 = n2; R3 = n3;
  }

  float* sp = sum + (size_t)(chain * NC + c) * 272;
  *reinterpret_cast<f32x4*>(&sp[i * 16 + 0]) = R0;
  *reinterpret_cast<f32x4*>(&sp[i * 16 + 4]) = R1;
  *reinterpret_cast<f32x4*>(&sp[i * 16 + 8]) = R2;
  *reinterpret_cast<f32x4*>(&sp[i * 16 + 12]) = R3;
  sp[256 + i] = q;
}

// ---------------------------------------------------------------------------
// scanB: serial scan over 64 chunk summaries per chain
// ---------------------------------------------------------------------------
__global__ __launch_bounds__(64) void scanB_kernel(const float* __restrict__ sum,
                                                   float* __restrict__ sinit) {
  int chain = blockIdx.x;
  int lane = threadIdx.x;
  int i = lane & 15;

  __shared__ float seg[2][2176];

  const float* gbase = sum + (size_t)chain * NC * 272;

  auto load_seg = [&](int s, int buf) {
#pragma unroll
    for (int r = 0; r < 9; ++r) {
      int idx = r * 256 + lane * 4;
      if (idx < 2176) {
        __builtin_amdgcn_global_load_lds(
            (const __attribute__((address_space(1))) void*)(gbase + (size_t)s * 2176 + idx),
            (__attribute__((address_space(3))) void*)(&seg[buf][r * 256]), 16, 0, 0);
      }
    }
  };

  load_seg(0, 0);
  asm volatile("s_waitcnt vmcnt(0)" ::: "memory");
  __builtin_amdgcn_sched_barrier(0);

  f32x4 S0 = (f32x4){0.f, 0.f, 0.f, 0.f}, S1 = S0, S2 = S0, S3 = S0;
  float own = 0.f;

  for (int sg = 0; sg < 8; ++sg) {
    int buf = sg & 1;
    if (sg + 1 < 8) load_seg(sg + 1, buf ^ 1);
#pragma unroll 1
    for (int cc = 0; cc < 8; ++cc) {
      int c = sg * 8 + cc;
      const float* Pb = &seg[buf][cc * 272];
      if (lane < 16) sinit[(size_t)(chain * NC + c) * 16 + i] = own;

      f32x4 p0 = *reinterpret_cast<const f32x4*>(&Pb[i * 16 + 0]);
      f32x4 p1 = *reinterpret_cast<const f32x4*>(&Pb[i * 16 + 4]);
      f32x4 p2 = *reinterpret_cast<const f32x4*>(&Pb[i * 16 + 8]);
      f32x4 p3 = *reinterpret_cast<const f32x4*>(&Pb[i * 16 + 12]);
      float qq = Pb[256 + i];

      float pa = fmaf(p0[0], S0[0], fmaf(p0[1], S0[1], fmaf(p0[2], S0[2], p0[3] * S0[3])));
      float pb = fmaf(p1[0], S1[0], fmaf(p1[1], S1[1], fmaf(p1[2], S1[2], p1[3] * S1[3])));
      float pc = fmaf(p2[0], S2[0], fmaf(p2[1], S2[1], fmaf(p2[2], S2[2], p2[3] * S2[3])));
      float pd = fmaf(p3[0], S3[0], fmaf(p3[1], S3[1], fmaf(p3[2], S3[2], p3[3] * S3[3])));
      float p = (pa + pb) + (pc + pd) + qq;
      own = p;

#pragma unroll
      for (int j = 0; j < 4; ++j) {
        S0[j] = __shfl(p, j, 64);
        S1[j] = __shfl(p, 4 + j, 64);
        S2[j] = __shfl(p, 8 + j, 64);
        S3[j] = __shfl(p, 12 + j, 64);
      }
    }
    if (sg + 1 < 8) {
      asm volatile("s_waitcnt vmcnt(0)" ::: "memory");
      __builtin_amdgcn_sched_barrier(0);
    }
  }
}

// ---------------------------------------------------------------------------
// scanC: re-run each chunk from its s_init, writing y
// ---------------------------------------------------------------------------
__global__ __launch_bounds__(256) void scanC_kernel(const bf16_t* __restrict__ lg,
                                                    const float* __restrict__ v,
                                                    const float* __restrict__ sinit,
                                                    bf16_t* __restrict__ y) {
  int bc = blockIdx.x;
  int b = bc >> 6;
  int c = bc & 63;
  int g = threadIdx.x >> 4;
  int i = threadIdx.x & 15;
  int h = blockIdx.y * 16 + g;
  int chain = b * 64 + h;

  __shared__ float Sb[16][16];

  const float* ip = sinit + (size_t)(chain * NC + c) * 16;
  f32x4 S0 = *reinterpret_cast<const f32x4*>(&ip[0]);
  f32x4 S1 = *reinterpret_cast<const f32x4*>(&ip[4]);
  f32x4 S2 = *reinterpret_cast<const f32x4*>(&ip[8]);
  f32x4 S3 = *reinterpret_cast<const f32x4*>(&ip[12]);

#pragma unroll 1
  for (int t = 0; t < CL; ++t) {
    int r = b * T_DIM + c * CL + t;
    const bf16_t* lp = lg + (size_t)r * NA + h * 272 + i * 17;
    float vval = v[(size_t)r * D_DIM + h * 16 + i];
    f32x4 a0, a1, a2, a3;
    float uu;
    softmax17(lp, vval, a0, a1, a2, a3, uu);

    float pa = fmaf(a0[0], S0[0], fmaf(a0[1], S0[1], fmaf(a0[2], S0[2], a0[3] * S0[3])));
    float pb = fmaf(a1[0], S1[0], fmaf(a1[1], S1[1], fmaf(a1[2], S1[2], a1[3] * S1[3])));
    float pc = fmaf(a2[0], S2[0], fmaf(a2[1], S2[1], fmaf(a2[2], S2[2], a2[3] * S2[3])));
    float pd = fmaf(a3[0], S3[0], fmaf(a3[1], S3[1], fmaf(a3[2], S3[2], a3[3] * S3[3])));
    float p = (pa + pb) + (pc + pd) + uu;

    y[(size_t)r * D_DIM + h * 16 + i] = (bf16_t)p;

    Sb[g][i] = p;
    asm volatile("s_waitcnt lgkmcnt(0)" ::: "memory");
    __builtin_amdgcn_sched_barrier(0);
    S0 = *reinterpret_cast<const f32x4*>(&Sb[g][0]);
    S1 = *reinterpret_cast<const f32x4*>(&Sb[g][4]);
    S2 = *reinterpret_cast<const f32x4*>(&Sb[g][8]);
    S3 = *reinterpret_cast<const f32x4*>(&Sb[g][12]);
  }
}

// ---------------------------------------------------------------------------
extern "C" void kernel_launch(void* const* d_in, const int* in_sizes, int n_in,
                              void* d_out, int out_size, void* d_ws, size_t ws_size,
                              hipStream_t stream) {
  const float* x      = (const float*)d_in[0];
  const float* norm_w = (const float*)d_in[1];
  const float* W_v    = (const float*)d_in[2];
  const float* W_a    = (const float*)d_in[3];
  const float* W_out  = (const float*)d_in[4];

  char* ws = (char*)d_ws;
  size_t off = 0;
  auto alloc = [&](size_t bytes) {
    void* p = ws + off;
    off += (bytes + 255) & ~(size_t)255;
    return p;
  };
  bf16_t* wcat = (bf16_t*)alloc((size_t)NCAT * D_DIM * 2);         // 37.75 MB
  bf16_t* wo_b = (bf16_t*)alloc((size_t)D_DIM * D_DIM * 2);        // 2 MB
  bf16_t* h_b  = (bf16_t*)alloc((size_t)NT * D_DIM * 2);           // 8 MB
  float*  v_f  = (float*)alloc((size_t)NT * D_DIM * 4);            // 16 MB
  bf16_t* lg_b = (bf16_t*)alloc((size_t)NT * NA * 2);              // 142.6 MB
  bf16_t* y_b  = (bf16_t*)alloc((size_t)NT * D_DIM * 2);           // 8 MB
  float*  sum_f   = (float*)alloc((size_t)256 * NC * 272 * 4);     // 17.8 MB
  float*  sinit_f = (float*)alloc((size_t)256 * NC * 16 * 4);      // 1.05 MB

  cvt_all_kernel<<<2048, 256, 0, stream>>>(W_a, W_v, W_out, wcat, wo_b);

  rmsnorm_kernel<<<NT, 256, 0, stream>>>(x, norm_w, h_b);

  gemm256_nt_kernel<<<dim3(NT / 256, NCAT / 256), 512, 0, stream>>>(h_b, wcat, lg_b, v_f);

  scanA_kernel<<<dim3(256, 4), 256, 0, stream>>>(lg_b, v_f, sum_f);
  scanB_kernel<<<256, 64, 0, stream>>>(sum_f, sinit_f);
  scanC_kernel<<<dim3(256, 4), 256, 0, stream>>>(lg_b, v_f, sinit_f, y_b);

  gemm_out_kernel<<<dim3(NT / 128, D_DIM / 128), 256, 0, stream>>>(
      y_b, wo_b, (float*)d_out, x, D_DIM, D_DIM);
}